// Round 1
// 203.633 us; speedup vs baseline: 1.0410x; 1.0410x over previous
//
#include <hip/hip_runtime.h>
#include <hip/hip_bf16.h>
#include <math.h>

#define DIMSZ 1024
#define NHEAD 16
#define HDIM 64
#define BATCH 2
#define SEQ 2048
#define NROWS (BATCH * SEQ)   // 4096

// softmax in exp2 domain: fold 1/sqrt(64) * log2(e) into Q at conversion
#define QSCALE 0.18033688011112042592f

typedef __attribute__((ext_vector_type(8))) short bf16x8;
typedef __attribute__((ext_vector_type(4))) float f32x4;

__device__ __forceinline__ int swz(int m) { return (m ^ (m >> 2)) & 3; }

__device__ __forceinline__ unsigned hipack(unsigned a, unsigned b) {
    return __builtin_amdgcn_perm(b, a, 0x07060302u);
}

// truncation split: hi = trunc-bf16(x), lo = trunc-bf16(x - hi)
__device__ __forceinline__ void cvt2(float x, float y, unsigned& h, unsigned& l) {
    unsigned ux = __float_as_uint(x), uy = __float_as_uint(y);
    h = hipack(ux, uy);
    float rx = x - __uint_as_float(ux & 0xFFFF0000u);
    float ry = y - __uint_as_float(uy & 0xFFFF0000u);
    l = hipack(__float_as_uint(rx), __float_as_uint(ry));
}

__device__ __forceinline__ void cvt8(const float4& f0, const float4& f1,
                                     uint4& hv, uint4& lv) {
    cvt2(f0.x, f0.y, hv.x, lv.x);
    cvt2(f0.z, f0.w, hv.y, lv.y);
    cvt2(f1.x, f1.y, hv.z, lv.z);
    cvt2(f1.z, f1.w, hv.w, lv.w);
}

__device__ __forceinline__ ushort f2bf(float x) {
    union { __hip_bfloat16 b; ushort u; } cv;
    cv.b = __float2bfloat16(x);
    return cv.u;
}

__device__ __forceinline__ void gld16(const void* g, void* l) {
    __builtin_amdgcn_global_load_lds((const __attribute__((address_space(1))) void*)g,
                                     (__attribute__((address_space(3))) void*)l,
                                     16, 0, 0);
}

// ---------------------------------------------------------------------------
// Fused convert: Wq/Wk/Wv -> truncation-split hi+lo (W-residual is the
// numerically-critical correlated term); x and Wo -> RNE bf16 hi-only
// (their residual terms average out: ~1e-5 contribution at the output).
// ---------------------------------------------------------------------------
__global__ __launch_bounds__(256) void convert_all(
    const float* __restrict__ x,
    const float* __restrict__ Wq, const float* __restrict__ Wk,
    const float* __restrict__ Wv, const float* __restrict__ Wo,
    ushort* __restrict__ Xhi,
    ushort* __restrict__ Whi, ushort* __restrict__ Wlo,
    ushort* __restrict__ Wohi)
{
    const int b = blockIdx.x;
    const float* src;
    ushort* hi;
    ushort* lo = nullptr;
    size_t off;
    if (b < 2048)      { src = x;  hi = Xhi;  off = (size_t)b * 2048; }
    else if (b < 2560) { src = Wq; hi = Whi;             lo = Wlo;             off = (size_t)(b - 2048) * 2048; }
    else if (b < 3072) { src = Wk; hi = Whi + (1 << 20); lo = Wlo + (1 << 20); off = (size_t)(b - 2560) * 2048; }
    else if (b < 3584) { src = Wv; hi = Whi + 2 * (1 << 20); lo = Wlo + 2 * (1 << 20); off = (size_t)(b - 3072) * 2048; }
    else               { src = Wo; hi = Wohi; off = (size_t)(b - 3584) * 2048; }

    const size_t i = off + (size_t)threadIdx.x * 8;
    const float4 f0 = *(const float4*)&src[i];
    const float4 f1 = *(const float4*)&src[i + 4];
    if (lo) {
        uint4 hv, lv;
        cvt8(f0, f1, hv, lv);
        *(uint4*)&hi[i] = hv;
        *(uint4*)&lo[i] = lv;
    } else {
        uint4 hv;
        hv.x = (unsigned)f2bf(f0.x) | ((unsigned)f2bf(f0.y) << 16);
        hv.y = (unsigned)f2bf(f0.z) | ((unsigned)f2bf(f0.w) << 16);
        hv.z = (unsigned)f2bf(f1.x) | ((unsigned)f2bf(f1.y) << 16);
        hv.w = (unsigned)f2bf(f1.z) | ((unsigned)f2bf(f1.w) << 16);
        *(uint4*)&hi[i] = hv;
    }
}

// ---------------------------------------------------------------------------
// Fused QKV GEMM: A = RNE-bf16 x (single plane), B = split W (hi+lo).
// 2 MFMAs per tile: ah*bh + ah*bl (x-residual term dropped — i.i.d. error,
// averages out; W-residual kept — correlated). Single-buffered pure-gld16,
// two-phase barrier (r9-proven). Per-iter LDS traffic 72KB vs r9's 96KB.
// ---------------------------------------------------------------------------
__global__ __launch_bounds__(256, 3) void qkv_gemm(
    const ushort* __restrict__ Xhi,
    const ushort* __restrict__ Whi, const ushort* __restrict__ Wlo,
    const float* __restrict__ bq, const float* __restrict__ bk,
    const float* __restrict__ bv,
    ushort* __restrict__ Qb, ushort* __restrict__ Kb, ushort* __restrict__ Vt)
{
    // K-loop: Ah[0..4095] Bh[4096..8191] Bl[8192..12287] (24KB)
    // epilogue reuse: 128 x 136 tile (17408 ushorts = 34KB) -> LDS block 34KB
    __shared__ __align__(16) ushort smem[17408];

    const int tid = threadIdx.x;
    const int wave = tid >> 6;
    const int lane = tid & 63;
    const int lm = lane & 15;
    const int lq = lane >> 4;
    const int wy = wave >> 1;
    const int wx = wave & 1;
    const int m0 = blockIdx.x * 128;
    const int nbase = blockIdx.y * 128;

    // staging map: thread t -> row r0 = t>>2 (and r0+64), LDS slot c = t&3,
    // global chunk g = c ^ swz(r0&15)
    const int c = tid & 3;
    const int r0 = tid >> 2;
    const int g = c ^ swz(r0 & 15);
    const ushort* gah = Xhi + (size_t)(m0 + r0) * DIMSZ + g * 8;
    const ushort* gbh = Whi + (size_t)(nbase + r0) * DIMSZ + g * 8;
    const ushort* gbl = Wlo + (size_t)(nbase + r0) * DIMSZ + g * 8;
    const int wofs = wave * 512;

    // frag read offsets
    const int fo = lm * 32 + (((lq ^ swz(lm)) & 3) << 3);
    int aofs[4], bofs[4];
#pragma unroll
    for (int i = 0; i < 4; ++i) {
        aofs[i] = (wy * 64 + i * 16) * 32 + fo;
        bofs[i] = (wx * 64 + i * 16) * 32 + fo;
    }

    f32x4 acc[4][4] = {};

    // stage k-tile 0
    {
        gld16(gah, smem + wofs);                 gld16(gah + 64 * DIMSZ, smem + 2048 + wofs);
        gld16(gbh, smem + 4096 + wofs);          gld16(gbh + 64 * DIMSZ, smem + 6144 + wofs);
        gld16(gbl, smem + 8192 + wofs);          gld16(gbl + 64 * DIMSZ, smem + 10240 + wofs);
    }

    for (int kk = 0; kk < 32; ++kk) {
        __syncthreads();   // barrier1: staging for tile kk landed (vmcnt drain)

        const ushort* Ah = smem;
        const ushort* Bh = smem + 4096;
        const ushort* Bl = smem + 8192;

        bf16x8 ahf[4], bhf[4], blf[4];
#pragma unroll
        for (int i = 0; i < 4; ++i) {
            ahf[i] = *(const bf16x8*)&Ah[aofs[i]];
            bhf[i] = *(const bf16x8*)&Bh[bofs[i]];
            blf[i] = *(const bf16x8*)&Bl[bofs[i]];
        }

        __syncthreads();   // barrier2: all frag reads done (lgkm only — cheap)

        if (kk + 1 < 32) {
            const int k0 = (kk + 1) * 32;
            gld16(gah + k0, smem + wofs);                 gld16(gah + 64 * DIMSZ + k0, smem + 2048 + wofs);
            gld16(gbh + k0, smem + 4096 + wofs);          gld16(gbh + 64 * DIMSZ + k0, smem + 6144 + wofs);
            gld16(gbl + k0, smem + 8192 + wofs);          gld16(gbl + 64 * DIMSZ + k0, smem + 10240 + wofs);
        }

#pragma unroll
        for (int i = 0; i < 4; ++i)
#pragma unroll
            for (int j = 0; j < 4; ++j) {
                acc[i][j] = __builtin_amdgcn_mfma_f32_16x16x32_bf16(ahf[i], bhf[j], acc[i][j], 0, 0, 0);
                acc[i][j] = __builtin_amdgcn_mfma_f32_16x16x32_bf16(ahf[i], blf[j], acc[i][j], 0, 0, 0);
            }
    }

    const int mat = blockIdx.y >> 3;      // 0:Q 1:K 2:V (block-uniform)
    const float* bias = (mat == 0) ? bq : (mat == 1) ? bk : bv;
    const int nloc0 = (blockIdx.y & 7) * 128;
    const int b = m0 >> 11;
    const int s0 = m0 & (SEQ - 1);
    ushort* sf = smem;                    // flat reuse (17408 ushorts)

    __syncthreads();   // K-loop traffic complete before smem reuse

    if (mat == 2) {
        // ---- V: transpose to [d][s], key-permuted within 32-blocks
#pragma unroll
        for (int j = 0; j < 4; ++j) {
            const int nc = nloc0 + wx * 64 + j * 16 + lm;
            const float bb = bias[nc];
            const int d = j * 16 + lm;
#pragma unroll
            for (int i = 0; i < 4; ++i) {
                // permuted position within 32-block: 8*lq + 4*(i&1) + rr
                const int ss = wy * 64 + (i >> 1) * 32 + lq * 8 + (i & 1) * 4;
                ushort4 pk;
                pk.x = f2bf(acc[i][j][0] + bb);
                pk.y = f2bf(acc[i][j][1] + bb);
                pk.z = f2bf(acc[i][j][2] + bb);
                pk.w = f2bf(acc[i][j][3] + bb);
                *(ushort4*)&sf[(wx * 64 + d) * 136 + ss] = pk;
            }
        }
        __syncthreads();
#pragma unroll
        for (int p = 0; p < 8; ++p) {
            const int idx = p * 256 + tid;
            const int row = idx >> 4;          // hh*64 + d
            const int hh = row >> 6;
            const int d = row & 63;
            const int sseg = (idx & 15) * 8;
            const uint4 v = *(const uint4*)&sf[row * 136 + sseg];
            const int hg = (nloc0 >> 6) + hh;
            *(uint4*)&Vt[((size_t)(b * NHEAD + hg) * HDIM + d) * SEQ + s0 + sseg] = v;
        }
    } else {
        // ---- Q/K: [s][d] tile in LDS, uint4 coalesced out
        ushort* dst = (mat == 0) ? Qb : Kb;
        const float sc = (mat == 0) ? QSCALE : 1.0f;
#pragma unroll
        for (int j = 0; j < 4; ++j) {
            const int col = wx * 64 + j * 16 + lm;      // 0..127
            const float bb = bias[nloc0 + col];
#pragma unroll
            for (int i = 0; i < 4; ++i) {
                const int rbase = wy * 64 + i * 16 + lq * 4;
#pragma unroll
                for (int rr = 0; rr < 4; ++rr)
                    sf[(rbase + rr) * 136 + col] = f2bf((acc[i][j][rr] + bb) * sc);
            }
        }
        __syncthreads();
#pragma unroll
        for (int p = 0; p < 8; ++p) {
            const int idx = p * 256 + tid;
            const int row = idx >> 4;          // local s: 0..127
            const int seg = idx & 15;          // 8-col segment
            const uint4 v = *(const uint4*)&sf[row * 136 + seg * 8];
            const int nc0 = nloc0 + seg * 8;
            const int h = nc0 >> 6;
            const int d = nc0 & 63;
            *(uint4*)&dst[((size_t)(b * NHEAD + h) * SEQ + s0 + row) * HDIM + d] = v;
        }
    }
}

// ---------------------------------------------------------------------------
// MFMA flash attention, S^T formulation. CTX out = single bf16 plane (RNE);
// plain-bf16 oproj error contribution ~2e-5 (out values are small).
//
// r1: 512-thread blocks (8 waves), 16 Q-rows per wave (was 256 thr / 32 rows).
// Same grid (16x32=512 blocks) => 2 blocks/CU but now 16 waves/CU (4/SIMD,
// ~50% occupancy vs 19%). Total MFMA/VALU/HBM work unchanged — pure overlap
// fix for the VALUBusy=44% / MfmaUtil=22% underutilization signature.
// Staging: 8 waves cover all 64 K/V rows in one gld16 pair per chunk.
// ---------------------------------------------------------------------------
__global__ __launch_bounds__(512, 4) void flash_attn_mfma(
    const ushort* __restrict__ Qb, const ushort* __restrict__ Kb,
    const ushort* __restrict__ Vt, ushort* __restrict__ CTXhi)
{
    __shared__ __align__(16) ushort Ks[2][4096];
    __shared__ __align__(16) ushort Vs[2][4096];

    const int tid = threadIdx.x;
    const int w = tid >> 6;        // 0..7
    const int l = tid & 63;
    const int lm = l & 15;
    const int lq = l >> 4;
    const int q0 = blockIdx.x * 128;
    const int bh = blockIdx.y;

    const ushort* Kg = Kb + (size_t)bh * SEQ * HDIM;
    const ushort* Vg = Vt + (size_t)bh * HDIM * SEQ;

    // staging: srow covers 0..63 across 8 waves; sc_ is the XOR-swizzled
    // 8-ushort chunk (matches koff read swizzle: slot (l&7) holds chunk
    // (l&7)^(row&7))
    const int srow = w * 8 + (l >> 3);
    const int sc_ = (l & 7) ^ ((l >> 3) & 7);

    bf16x8 qf[2];
#pragma unroll
    for (int kt = 0; kt < 2; ++kt)
        qf[kt] = *(const bf16x8*)&Qb[((size_t)bh * SEQ + q0 + w * 16 + lm) * HDIM + kt * 32 + lq * 8];

    int koff[4][2];
#pragma unroll
    for (int t = 0; t < 4; ++t)
#pragma unroll
        for (int kt = 0; kt < 2; ++kt)
            koff[t][kt] = (t * 16 + lm) * 64 + (((kt * 4 + lq) ^ (lm & 7)) << 3);

    f32x4 o[4] = {};
    float l_ = 0.0f;

    // stage chunk 0
    gld16(Kg + (size_t)srow * HDIM + sc_ * 8, &Ks[0][0] + w * 8 * 64);
    gld16(Vg + (size_t)srow * SEQ + sc_ * 8, &Vs[0][0] + w * 8 * 64);

    for (int ch = 0; ch < SEQ / 64; ++ch) {
        __syncthreads();

        if (ch + 1 < SEQ / 64) {
            const int kc = (ch + 1) * 64;
            ushort* kb_n = &Ks[(ch + 1) & 1][0];
            ushort* vb_n = &Vs[(ch + 1) & 1][0];
            gld16(Kg + (size_t)(kc + srow) * HDIM + sc_ * 8, kb_n + w * 8 * 64);
            gld16(Vg + (size_t)srow * SEQ + kc + sc_ * 8, vb_n + w * 8 * 64);
        }

        const ushort* kb = &Ks[ch & 1][0];
        const ushort* vb = &Vs[ch & 1][0];

        f32x4 st[4] = {};
#pragma unroll
        for (int ct = 0; ct < 4; ++ct)
#pragma unroll
            for (int kt = 0; kt < 2; ++kt) {
                const bf16x8 kf = *(const bf16x8*)&kb[koff[ct][kt]];
                st[ct] = __builtin_amdgcn_mfma_f32_16x16x32_bf16(kf, qf[kt], st[ct], 0, 0, 0);
            }

        {
            float ls = 0.0f;
#pragma unroll
            for (int ct = 0; ct < 4; ++ct)
#pragma unroll
                for (int r = 0; r < 4; ++r) {
                    const float p = __builtin_amdgcn_exp2f(st[ct][r]);
                    st[ct][r] = p;
                    ls += p;
                }
            ls += __shfl_xor(ls, 16, 64);
            ls += __shfl_xor(ls, 32, 64);
            l_ += ls;
        }

        bf16x8 pf[2];
#pragma unroll
        for (int kt2 = 0; kt2 < 2; ++kt2) {
            union { bf16x8 v; ushort u[8]; } pk;
#pragma unroll
            for (int t = 0; t < 2; ++t)
#pragma unroll
                for (int r = 0; r < 4; ++r)
                    pk.u[t * 4 + r] = f2bf(st[kt2 * 2 + t][r]);
            pf[kt2] = pk.v;
        }

#pragma unroll
        for (int dt = 0; dt < 4; ++dt)
#pragma unroll
            for (int kt2 = 0; kt2 < 2; ++kt2) {
                const bf16x8 vf = *(const bf16x8*)&vb[koff[dt][kt2]];
                o[dt] = __builtin_amdgcn_mfma_f32_16x16x32_bf16(pf[kt2], vf, o[dt], 0, 0, 0);
            }
    }

    const int b = bh >> 4;
    const int h = bh & 15;
    const float linv_me = 1.0f / l_;
#pragma unroll
    for (int r = 0; r < 4; ++r) {
        const float lr = __shfl(linv_me, lq * 4 + r, 64);
        const int srow_ = q0 + w * 16 + lq * 4 + r;
        const size_t base = ((size_t)b * SEQ + srow_) * DIMSZ + h * HDIM;
#pragma unroll
        for (int dt = 0; dt < 4; ++dt)
            CTXhi[base + dt * 16 + lm] = f2bf(o[dt][r] * lr);
    }
}

// ---------------------------------------------------------------------------
// Output projection: PLAIN bf16 (CTXhi x Wohi, 1 MFMA/tile). Single-buffer
// two-phase-barrier pure-gld16 (r9 structure). 64x128 tiles, 512 blocks,
// 12KB LDS.
// ---------------------------------------------------------------------------
__global__ __launch_bounds__(256) void oproj_gemm(
    const ushort* __restrict__ Ahi_g, const ushort* __restrict__ Bhi_g,
    const float* __restrict__ bias, float* __restrict__ out)
{
    __shared__ __align__(16) ushort smem[6144];   // Ah[2048] Bh[4096] = 12KB

    const int tid = threadIdx.x;
    const int wave = tid >> 6;
    const int lane = tid & 63;
    const int lm = lane & 15;
    const int lq = lane >> 4;
    const int wy = wave >> 1;
    const int wx = wave & 1;
    const int m0 = blockIdx.x * 64;
    const int n0 = blockIdx.y * 128;

    const int c = tid & 3;
    const int r0 = tid >> 2;
    const int g = c ^ swz(r0 & 15);
    const ushort* gah = Ahi_g + (size_t)(m0 + r0) * DIMSZ + g * 8;
    const ushort* gbh = Bhi_g + (size_t)(n0 + r0) * DIMSZ + g * 8;
    const int wofs = wave * 512;

    const int fo = lm * 32 + (((lq ^ swz(lm)) & 3) << 3);
    int aofs[2], bofs[4];
#pragma unroll
    for (int i = 0; i < 2; ++i) aofs[i] = (wy * 32 + i * 16) * 32 + fo;
#pragma unroll
    for (int j = 0; j < 4; ++j) bofs[j] = (wx * 64 + j * 16) * 32 + fo;

    f32x4 acc[2][4] = {};

    {
        gld16(gah, smem + wofs);
        gld16(gbh, smem + 2048 + wofs);   gld16(gbh + 64 * DIMSZ, smem + 4096 + wofs);
    }

    for (int kk = 0; kk < 32; ++kk) {
        __syncthreads();   // staged

        bf16x8 ahf[2], bhf[4];
#pragma unroll
        for (int i = 0; i < 2; ++i) ahf[i] = *(const bf16x8*)&smem[aofs[i]];
#pragma unroll
        for (int j = 0; j < 4; ++j) bhf[j] = *(const bf16x8*)&smem[2048 + bofs[j]];

        __syncthreads();   // reads done

        if (kk + 1 < 32) {
            const int k0 = (kk + 1) * 32;
            gld16(gah + k0, smem + wofs);
            gld16(gbh + k0, smem + 2048 + wofs);   gld16(gbh + 64 * DIMSZ + k0, smem + 4096 + wofs);
        }

#pragma unroll
        for (int i = 0; i < 2; ++i)
#pragma unroll
            for (int j = 0; j < 4; ++j)
                acc[i][j] = __builtin_amdgcn_mfma_f32_16x16x32_bf16(ahf[i], bhf[j], acc[i][j], 0, 0, 0);
    }

#pragma unroll
    for (int j = 0; j < 4; ++j) {
        const int nc = n0 + wx * 64 + j * 16 + lm;
        const float bb = bias[nc];
#pragma unroll
        for (int i = 0; i < 2; ++i) {
            const int mb = m0 + wy * 32 + i * 16 + lq * 4;
#pragma unroll
            for (int rr = 0; rr < 4; ++rr)
                out[(size_t)(mb + rr) * DIMSZ + nc] = acc[i][j][rr] + bb;
        }
    }
}

// ---------------------------------------------------------------------------
extern "C" void kernel_launch(void* const* d_in, const int* in_sizes, int n_in,
                              void* d_out, int out_size, void* d_ws, size_t ws_size,
                              hipStream_t stream)
{
    const float* x  = (const float*)d_in[0];
    const float* Wq = (const float*)d_in[1];
    const float* bq = (const float*)d_in[2];
    const float* Wk = (const float*)d_in[3];
    const float* bk = (const float*)d_in[4];
    const float* Wv = (const float*)d_in[5];
    const float* bv = (const float*)d_in[6];
    const float* Wo = (const float*)d_in[7];
    const float* bo = (const float*)d_in[8];
    float* out = (float*)d_out;

    const size_t elems = (size_t)NROWS * DIMSZ;   // 4M
    ushort* Qb    = (ushort*)d_ws;                // 8MB
    ushort* Kb    = Qb + elems;                   // 8MB
    ushort* Vt    = Kb + elems;                   // 8MB
    ushort* CTXhi = Vt + elems;                   // 8MB (overlay: Xhi)
    ushort* Whi   = CTXhi + elems;                // 6MB
    ushort* Wlo   = Whi + 3 * (1 << 20);          // 6MB
    ushort* Wohi  = Wlo + 3 * (1 << 20);          // 2MB  (peak 46MB)
    ushort* Xhi   = CTXhi;                        // dead before flash writes CTX

    convert_all<<<4096, 256, 0, stream>>>(x, Wq, Wk, Wv, Wo,
                                          Xhi, Whi, Wlo, Wohi);

    qkv_gemm<<<dim3(32, 24), 256, 0, stream>>>(Xhi, Whi, Wlo, bq, bk, bv, Qb, Kb, Vt);

    flash_attn_mfma<<<dim3(SEQ / 128, BATCH * NHEAD), 512, 0, stream>>>(Qb, Kb, Vt, CTXhi);

    oproj_gemm<<<dim3(64, 8), 256, 0, stream>>>(CTXhi, Wohi, bo, out);
}

// Round 2
// 182.360 us; speedup vs baseline: 1.1624x; 1.1167x over previous
//
#include <hip/hip_runtime.h>
#include <hip/hip_bf16.h>
#include <math.h>

#define DIMSZ 1024
#define NHEAD 16
#define HDIM 64
#define BATCH 2
#define SEQ 2048
#define NROWS (BATCH * SEQ)   // 4096

// softmax in exp2 domain: fold 1/sqrt(64) * log2(e) into Q at conversion
#define QSCALE 0.18033688011112042592f

typedef __attribute__((ext_vector_type(8))) _Float16 f16x8;
typedef __attribute__((ext_vector_type(4))) float f32x4;

__device__ __forceinline__ int swz(int m) { return (m ^ (m >> 2)) & 3; }

// float -> fp16 RNE, as bit pattern
__device__ __forceinline__ ushort f2h(float x) {
    union { _Float16 h; ushort u; } cv;
    cv.h = (_Float16)x;
    return cv.u;
}

__device__ __forceinline__ void gld16(const void* g, void* l) {
    __builtin_amdgcn_global_load_lds((const __attribute__((address_space(1))) void*)g,
                                     (__attribute__((address_space(3))) void*)l,
                                     16, 0, 0);
}

// ---------------------------------------------------------------------------
// Convert everything to fp16 single-plane (r2). fp16 rel err 2^-11 beats the
// old scheme's dominant term (x at bf16 RNE, 2^-9); W errors at 2^-11 sum to
// ~1.4e-4 over K=1024 — net accuracy slightly BETTER than bf16+split, at
// HALF the qkv MFMA work.
// ---------------------------------------------------------------------------
__global__ __launch_bounds__(256) void convert_all(
    const float* __restrict__ x,
    const float* __restrict__ Wq, const float* __restrict__ Wk,
    const float* __restrict__ Wv, const float* __restrict__ Wo,
    ushort* __restrict__ Xh, ushort* __restrict__ Wh, ushort* __restrict__ Woh)
{
    const int b = blockIdx.x;
    const float* src;
    ushort* dst;
    size_t off;
    if (b < 2048)      { src = x;  dst = Xh;             off = (size_t)b * 2048; }
    else if (b < 2560) { src = Wq; dst = Wh;             off = (size_t)(b - 2048) * 2048; }
    else if (b < 3072) { src = Wk; dst = Wh + (1 << 20); off = (size_t)(b - 2560) * 2048; }
    else if (b < 3584) { src = Wv; dst = Wh + 2 * (1 << 20); off = (size_t)(b - 3072) * 2048; }
    else               { src = Wo; dst = Woh;            off = (size_t)(b - 3584) * 2048; }

    const size_t i = off + (size_t)threadIdx.x * 8;
    const float4 f0 = *(const float4*)&src[i];
    const float4 f1 = *(const float4*)&src[i + 4];
    uint4 hv;
    hv.x = (unsigned)f2h(f0.x) | ((unsigned)f2h(f0.y) << 16);
    hv.y = (unsigned)f2h(f0.z) | ((unsigned)f2h(f0.w) << 16);
    hv.z = (unsigned)f2h(f1.x) | ((unsigned)f2h(f1.y) << 16);
    hv.w = (unsigned)f2h(f1.z) | ((unsigned)f2h(f1.w) << 16);
    *(uint4*)&dst[i] = hv;
}

// ---------------------------------------------------------------------------
// Fused QKV GEMM, fp16 single-plane: 1 MFMA per tile (was 2 with bf16 split).
// Single-buffered pure-gld16, two-phase barrier (r9-proven structure,
// MfmaUtil ~38% = structural ceiling; halving MFMA count halves time).
// Per-iter staging 16KB (was 24KB).
// ---------------------------------------------------------------------------
__global__ __launch_bounds__(256, 3) void qkv_gemm(
    const ushort* __restrict__ Xh,
    const ushort* __restrict__ Wh,
    const float* __restrict__ bq, const float* __restrict__ bk,
    const float* __restrict__ bv,
    ushort* __restrict__ Qb, ushort* __restrict__ Kb, ushort* __restrict__ Vt)
{
    // K-loop: Ah[0..4095] Bh[4096..8191] (16KB)
    // epilogue reuse: 128 x 136 tile (17408 ushorts = 34KB) -> LDS block 34KB
    __shared__ __align__(16) ushort smem[17408];

    const int tid = threadIdx.x;
    const int wave = tid >> 6;
    const int lane = tid & 63;
    const int lm = lane & 15;
    const int lq = lane >> 4;
    const int wy = wave >> 1;
    const int wx = wave & 1;
    const int m0 = blockIdx.x * 128;
    const int nbase = blockIdx.y * 128;

    // staging map: thread t -> row r0 = t>>2 (and r0+64), LDS slot c = t&3,
    // global chunk g = c ^ swz(r0&15)
    const int c = tid & 3;
    const int r0 = tid >> 2;
    const int g = c ^ swz(r0 & 15);
    const ushort* gah = Xh + (size_t)(m0 + r0) * DIMSZ + g * 8;
    const ushort* gbh = Wh + (size_t)(nbase + r0) * DIMSZ + g * 8;
    const int wofs = wave * 512;

    // frag read offsets
    const int fo = lm * 32 + (((lq ^ swz(lm)) & 3) << 3);
    int aofs[4], bofs[4];
#pragma unroll
    for (int i = 0; i < 4; ++i) {
        aofs[i] = (wy * 64 + i * 16) * 32 + fo;
        bofs[i] = (wx * 64 + i * 16) * 32 + fo;
    }

    f32x4 acc[4][4] = {};

    // stage k-tile 0
    {
        gld16(gah, smem + wofs);                 gld16(gah + 64 * DIMSZ, smem + 2048 + wofs);
        gld16(gbh, smem + 4096 + wofs);          gld16(gbh + 64 * DIMSZ, smem + 6144 + wofs);
    }

    for (int kk = 0; kk < 32; ++kk) {
        __syncthreads();   // barrier1: staging for tile kk landed (vmcnt drain)

        const ushort* Ah = smem;
        const ushort* Bh = smem + 4096;

        f16x8 ahf[4], bhf[4];
#pragma unroll
        for (int i = 0; i < 4; ++i) {
            ahf[i] = *(const f16x8*)&Ah[aofs[i]];
            bhf[i] = *(const f16x8*)&Bh[bofs[i]];
        }

        __syncthreads();   // barrier2: all frag reads done (lgkm only — cheap)

        if (kk + 1 < 32) {
            const int k0 = (kk + 1) * 32;
            gld16(gah + k0, smem + wofs);                 gld16(gah + 64 * DIMSZ + k0, smem + 2048 + wofs);
            gld16(gbh + k0, smem + 4096 + wofs);          gld16(gbh + 64 * DIMSZ + k0, smem + 6144 + wofs);
        }

#pragma unroll
        for (int i = 0; i < 4; ++i)
#pragma unroll
            for (int j = 0; j < 4; ++j)
                acc[i][j] = __builtin_amdgcn_mfma_f32_16x16x32_f16(ahf[i], bhf[j], acc[i][j], 0, 0, 0);
    }

    const int mat = blockIdx.y >> 3;      // 0:Q 1:K 2:V (block-uniform)
    const float* bias = (mat == 0) ? bq : (mat == 1) ? bk : bv;
    const int nloc0 = (blockIdx.y & 7) * 128;
    const int b = m0 >> 11;
    const int s0 = m0 & (SEQ - 1);
    ushort* sf = smem;                    // flat reuse (17408 ushorts)

    __syncthreads();   // K-loop traffic complete before smem reuse

    if (mat == 2) {
        // ---- V: transpose to [d][s], key-permuted within 32-blocks
#pragma unroll
        for (int j = 0; j < 4; ++j) {
            const int nc = nloc0 + wx * 64 + j * 16 + lm;
            const float bb = bias[nc];
            const int d = j * 16 + lm;
#pragma unroll
            for (int i = 0; i < 4; ++i) {
                // permuted position within 32-block: 8*lq + 4*(i&1) + rr
                const int ss = wy * 64 + (i >> 1) * 32 + lq * 8 + (i & 1) * 4;
                ushort4 pk;
                pk.x = f2h(acc[i][j][0] + bb);
                pk.y = f2h(acc[i][j][1] + bb);
                pk.z = f2h(acc[i][j][2] + bb);
                pk.w = f2h(acc[i][j][3] + bb);
                *(ushort4*)&sf[(wx * 64 + d) * 136 + ss] = pk;
            }
        }
        __syncthreads();
#pragma unroll
        for (int p = 0; p < 8; ++p) {
            const int idx = p * 256 + tid;
            const int row = idx >> 4;          // hh*64 + d
            const int hh = row >> 6;
            const int d = row & 63;
            const int sseg = (idx & 15) * 8;
            const uint4 v = *(const uint4*)&sf[row * 136 + sseg];
            const int hg = (nloc0 >> 6) + hh;
            *(uint4*)&Vt[((size_t)(b * NHEAD + hg) * HDIM + d) * SEQ + s0 + sseg] = v;
        }
    } else {
        // ---- Q/K: [s][d] tile in LDS, uint4 coalesced out
        ushort* dst = (mat == 0) ? Qb : Kb;
        const float sc = (mat == 0) ? QSCALE : 1.0f;
#pragma unroll
        for (int j = 0; j < 4; ++j) {
            const int col = wx * 64 + j * 16 + lm;      // 0..127
            const float bb = bias[nloc0 + col];
#pragma unroll
            for (int i = 0; i < 4; ++i) {
                const int rbase = wy * 64 + i * 16 + lq * 4;
#pragma unroll
                for (int rr = 0; rr < 4; ++rr)
                    sf[(rbase + rr) * 136 + col] = f2h((acc[i][j][rr] + bb) * sc);
            }
        }
        __syncthreads();
#pragma unroll
        for (int p = 0; p < 8; ++p) {
            const int idx = p * 256 + tid;
            const int row = idx >> 4;          // local s: 0..127
            const int seg = idx & 15;          // 8-col segment
            const uint4 v = *(const uint4*)&sf[row * 136 + seg * 8];
            const int nc0 = nloc0 + seg * 8;
            const int h = nc0 >> 6;
            const int d = nc0 & 63;
            *(uint4*)&dst[((size_t)(b * NHEAD + h) * SEQ + s0 + row) * HDIM + d] = v;
        }
    }
}

// ---------------------------------------------------------------------------
// MFMA flash attention, S^T formulation, fp16 operands. CTX out = fp16.
// 512-thread blocks (8 waves), 16 Q-rows per wave (r1 occupancy fix: 4
// waves/SIMD). Staging: 8 waves cover all 64 K/V rows per chunk.
// ---------------------------------------------------------------------------
__global__ __launch_bounds__(512, 4) void flash_attn_mfma(
    const ushort* __restrict__ Qb, const ushort* __restrict__ Kb,
    const ushort* __restrict__ Vt, ushort* __restrict__ CTXh)
{
    __shared__ __align__(16) ushort Ks[2][4096];
    __shared__ __align__(16) ushort Vs[2][4096];

    const int tid = threadIdx.x;
    const int w = tid >> 6;        // 0..7
    const int l = tid & 63;
    const int lm = l & 15;
    const int lq = l >> 4;
    const int q0 = blockIdx.x * 128;
    const int bh = blockIdx.y;

    const ushort* Kg = Kb + (size_t)bh * SEQ * HDIM;
    const ushort* Vg = Vt + (size_t)bh * HDIM * SEQ;

    // staging: srow covers 0..63 across 8 waves; sc_ is the XOR-swizzled
    // 8-ushort chunk (matches koff read swizzle)
    const int srow = w * 8 + (l >> 3);
    const int sc_ = (l & 7) ^ ((l >> 3) & 7);

    f16x8 qf[2];
#pragma unroll
    for (int kt = 0; kt < 2; ++kt)
        qf[kt] = *(const f16x8*)&Qb[((size_t)bh * SEQ + q0 + w * 16 + lm) * HDIM + kt * 32 + lq * 8];

    int koff[4][2];
#pragma unroll
    for (int t = 0; t < 4; ++t)
#pragma unroll
        for (int kt = 0; kt < 2; ++kt)
            koff[t][kt] = (t * 16 + lm) * 64 + (((kt * 4 + lq) ^ (lm & 7)) << 3);

    f32x4 o[4] = {};
    float l_ = 0.0f;

    // stage chunk 0
    gld16(Kg + (size_t)srow * HDIM + sc_ * 8, &Ks[0][0] + w * 8 * 64);
    gld16(Vg + (size_t)srow * SEQ + sc_ * 8, &Vs[0][0] + w * 8 * 64);

    for (int ch = 0; ch < SEQ / 64; ++ch) {
        __syncthreads();

        if (ch + 1 < SEQ / 64) {
            const int kc = (ch + 1) * 64;
            ushort* kb_n = &Ks[(ch + 1) & 1][0];
            ushort* vb_n = &Vs[(ch + 1) & 1][0];
            gld16(Kg + (size_t)(kc + srow) * HDIM + sc_ * 8, kb_n + w * 8 * 64);
            gld16(Vg + (size_t)srow * SEQ + kc + sc_ * 8, vb_n + w * 8 * 64);
        }

        const ushort* kb = &Ks[ch & 1][0];
        const ushort* vb = &Vs[ch & 1][0];

        f32x4 st[4] = {};
#pragma unroll
        for (int ct = 0; ct < 4; ++ct)
#pragma unroll
            for (int kt = 0; kt < 2; ++kt) {
                const f16x8 kf = *(const f16x8*)&kb[koff[ct][kt]];
                st[ct] = __builtin_amdgcn_mfma_f32_16x16x32_f16(kf, qf[kt], st[ct], 0, 0, 0);
            }

        {
            float ls = 0.0f;
#pragma unroll
            for (int ct = 0; ct < 4; ++ct)
#pragma unroll
                for (int r = 0; r < 4; ++r) {
                    const float p = __builtin_amdgcn_exp2f(st[ct][r]);
                    st[ct][r] = p;
                    ls += p;
                }
            ls += __shfl_xor(ls, 16, 64);
            ls += __shfl_xor(ls, 32, 64);
            l_ += ls;
        }

        f16x8 pf[2];
#pragma unroll
        for (int kt2 = 0; kt2 < 2; ++kt2) {
            union { f16x8 v; ushort u[8]; } pk;
#pragma unroll
            for (int t = 0; t < 2; ++t)
#pragma unroll
                for (int r = 0; r < 4; ++r)
                    pk.u[t * 4 + r] = f2h(st[kt2 * 2 + t][r]);
            pf[kt2] = pk.v;
        }

#pragma unroll
        for (int dt = 0; dt < 4; ++dt)
#pragma unroll
            for (int kt2 = 0; kt2 < 2; ++kt2) {
                const f16x8 vf = *(const f16x8*)&vb[koff[dt][kt2]];
                o[dt] = __builtin_amdgcn_mfma_f32_16x16x32_f16(pf[kt2], vf, o[dt], 0, 0, 0);
            }
    }

    const int b = bh >> 4;
    const int h = bh & 15;
    const float linv_me = 1.0f / l_;
#pragma unroll
    for (int r = 0; r < 4; ++r) {
        const float lr = __shfl(linv_me, lq * 4 + r, 64);
        const int srow_ = q0 + w * 16 + lq * 4 + r;
        const size_t base = ((size_t)b * SEQ + srow_) * DIMSZ + h * HDIM;
#pragma unroll
        for (int dt = 0; dt < 4; ++dt)
            CTXh[base + dt * 16 + lm] = f2h(o[dt][r] * lr);
    }
}

// ---------------------------------------------------------------------------
// Output projection: fp16 (CTXh x Woh, 1 MFMA/tile). Single-buffer
// two-phase-barrier pure-gld16. 64x128 tiles, 512 blocks, 12KB LDS.
// ---------------------------------------------------------------------------
__global__ __launch_bounds__(256) void oproj_gemm(
    const ushort* __restrict__ Ah_g, const ushort* __restrict__ Bh_g,
    const float* __restrict__ bias, float* __restrict__ out)
{
    __shared__ __align__(16) ushort smem[6144];   // Ah[2048] Bh[4096] = 12KB

    const int tid = threadIdx.x;
    const int wave = tid >> 6;
    const int lane = tid & 63;
    const int lm = lane & 15;
    const int lq = lane >> 4;
    const int wy = wave >> 1;
    const int wx = wave & 1;
    const int m0 = blockIdx.x * 64;
    const int n0 = blockIdx.y * 128;

    const int c = tid & 3;
    const int r0 = tid >> 2;
    const int g = c ^ swz(r0 & 15);
    const ushort* gah = Ah_g + (size_t)(m0 + r0) * DIMSZ + g * 8;
    const ushort* gbh = Bh_g + (size_t)(n0 + r0) * DIMSZ + g * 8;
    const int wofs = wave * 512;

    const int fo = lm * 32 + (((lq ^ swz(lm)) & 3) << 3);
    int aofs[2], bofs[4];
#pragma unroll
    for (int i = 0; i < 2; ++i) aofs[i] = (wy * 32 + i * 16) * 32 + fo;
#pragma unroll
    for (int j = 0; j < 4; ++j) bofs[j] = (wx * 64 + j * 16) * 32 + fo;

    f32x4 acc[2][4] = {};

    {
        gld16(gah, smem + wofs);
        gld16(gbh, smem + 2048 + wofs);   gld16(gbh + 64 * DIMSZ, smem + 4096 + wofs);
    }

    for (int kk = 0; kk < 32; ++kk) {
        __syncthreads();   // staged

        f16x8 ahf[2], bhf[4];
#pragma unroll
        for (int i = 0; i < 2; ++i) ahf[i] = *(const f16x8*)&smem[aofs[i]];
#pragma unroll
        for (int j = 0; j < 4; ++j) bhf[j] = *(const f16x8*)&smem[2048 + bofs[j]];

        __syncthreads();   // reads done

        if (kk + 1 < 32) {
            const int k0 = (kk + 1) * 32;
            gld16(gah + k0, smem + wofs);
            gld16(gbh + k0, smem + 2048 + wofs);   gld16(gbh + 64 * DIMSZ + k0, smem + 4096 + wofs);
        }

#pragma unroll
        for (int i = 0; i < 2; ++i)
#pragma unroll
            for (int j = 0; j < 4; ++j)
                acc[i][j] = __builtin_amdgcn_mfma_f32_16x16x32_f16(ahf[i], bhf[j], acc[i][j], 0, 0, 0);
    }

#pragma unroll
    for (int j = 0; j < 4; ++j) {
        const int nc = n0 + wx * 64 + j * 16 + lm;
        const float bb = bias[nc];
#pragma unroll
        for (int i = 0; i < 2; ++i) {
            const int mb = m0 + wy * 32 + i * 16 + lq * 4;
#pragma unroll
            for (int rr = 0; rr < 4; ++rr)
                out[(size_t)(mb + rr) * DIMSZ + nc] = acc[i][j][rr] + bb;
        }
    }
}

// ---------------------------------------------------------------------------
extern "C" void kernel_launch(void* const* d_in, const int* in_sizes, int n_in,
                              void* d_out, int out_size, void* d_ws, size_t ws_size,
                              hipStream_t stream)
{
    const float* x  = (const float*)d_in[0];
    const float* Wq = (const float*)d_in[1];
    const float* bq = (const float*)d_in[2];
    const float* Wk = (const float*)d_in[3];
    const float* bk = (const float*)d_in[4];
    const float* Wv = (const float*)d_in[5];
    const float* bv = (const float*)d_in[6];
    const float* Wo = (const float*)d_in[7];
    const float* bo = (const float*)d_in[8];
    float* out = (float*)d_out;

    const size_t elems = (size_t)NROWS * DIMSZ;   // 4M
    ushort* Qb   = (ushort*)d_ws;                 // 8MB
    ushort* Kb   = Qb + elems;                    // 8MB
    ushort* Vt   = Kb + elems;                    // 8MB
    ushort* CTXh = Vt + elems;                    // 8MB (overlay: Xh)
    ushort* Wh   = CTXh + elems;                  // 6MB
    ushort* Woh  = Wh + 3 * (1 << 20);            // 2MB  (peak 40MB)
    ushort* Xh   = CTXh;                          // dead before flash writes CTX

    convert_all<<<4096, 256, 0, stream>>>(x, Wq, Wk, Wv, Wo, Xh, Wh, Woh);

    qkv_gemm<<<dim3(32, 24), 256, 0, stream>>>(Xh, Wh, bq, bk, bv, Qb, Kb, Vt);

    flash_attn_mfma<<<dim3(SEQ / 128, BATCH * NHEAD), 512, 0, stream>>>(Qb, Kb, Vt, CTXh);

    oproj_gemm<<<dim3(64, 8), 256, 0, stream>>>(CTXh, Woh, bo, out);
}